// Round 8
// baseline (184.310 us; speedup 1.0000x reference)
//
#include <hip/hip_runtime.h>
#include <math.h>

// Problem constants (reference: B=4, S=512, E=512, H=8, DH=64, HID=128)
#define BATCH 4
#define SEQ   512
#define EMB   512
#define NH    8
#define DHD   64
#define HIDN  128
#define ALPHA 0.1f
#define EPSS  0.05f

// LUT for the pointwise conv-chain -> sigmoid function of `scaled`
#define LUTN  2048
#define XMIN  (-0.4f)
#define XSTEP (0.8f / LUTN)

typedef __attribute__((ext_vector_type(8))) short  bf16x8;
typedef __attribute__((ext_vector_type(4))) float  f32x4;
#define MFMA(a,b,c) __builtin_amdgcn_mfma_f32_16x16x32_bf16((a),(b),(c),0,0,0)

__device__ __forceinline__ unsigned short f2bf(float f) {
    union { float f; unsigned u; } v; v.f = f;
    unsigned r = v.u + 0x7fffu + ((v.u >> 16) & 1u);   // RNE; inputs finite
    return (unsigned short)(r >> 16);
}
__device__ __forceinline__ float bf2f(unsigned short h) {
    union { unsigned u; float f; } v; v.u = ((unsigned)h) << 16;
    return v.f;
}
__device__ __forceinline__ float f16tof(unsigned short h) {
    union { unsigned short s; _Float16 f; } v; v.s = h; return (float)v.f;
}
__device__ __forceinline__ unsigned short ftof16(float f) {
    union { unsigned short s; _Float16 f; } v; v.f = (_Float16)f; return v.s;
}

// async global->LDS, 16B per lane; LDS dst = uniform base + lane*16
__device__ __forceinline__ void async_lds16(const unsigned short* g, unsigned short* l) {
    __builtin_amdgcn_global_load_lds(
        (const __attribute__((address_space(1))) void*)g,
        (__attribute__((address_space(3))) void*)l, 16, 0, 0);
}

// pack 8 f32 -> bf16x8, hi part or lo remainder (exactly prep's split math)
__device__ __forceinline__ bf16x8 pack8(const float4 v0, const float4 v1, bool lo) {
    const float vv[8] = { v0.x, v0.y, v0.z, v0.w, v1.x, v1.y, v1.z, v1.w };
    bf16x8 pk;
    #pragma unroll
    for (int i = 0; i < 8; i++) {
        const unsigned short h = f2bf(vv[i]);
        pk[i] = (short)(lo ? f2bf(vv[i] - bf2f(h)) : h);
    }
    return pk;
}

// ---------------- BK=64 GEMM core (single-buffer, 2 barriers/step) -------
// (used by gemm_scores; qkv now has its own reg-staged variant)
template<int KS, int UN, int MT>
__device__ __forceinline__ void gemm_core64(
    const unsigned short* __restrict__ A, const unsigned short* __restrict__ B,
    int m0, int n0, unsigned short* sA, unsigned short* sB, f32x4 (&acc)[2][4])
{
    const int K = KS * 64;
    const int tid = threadIdx.x, w = tid >> 6, lane = tid & 63;
    const int quad = lane >> 4, r = lane & 15;
    const int wm = w >> 1, wn = w & 1;
    const int lrow = lane >> 3, lc = lane & 7;
    const int sc = lc ^ lrow;                     // swizzled global chunk
    constexpr int AF = MT / 32;                   // A frags per wave
    constexpr int NB = UN;                        // B staging calls per wave

    const unsigned short* ag[2]; unsigned short* dAu[2];
    #pragma unroll
    for (int c = 0; c < AF; c++) {
        const int rb = w * (8 * AF) + c * 8;
        ag[c]  = A + (long)(m0 + rb + lrow) * K + sc * 8;
        dAu[c] = sA + rb * 64;
    }
    const unsigned short* bg[4]; unsigned short* dBu[4];
    #pragma unroll
    for (int c = 0; c < NB; c++) {
        const int rb = w * (8 * NB) + c * 8;
        bg[c]  = B + (long)(n0 + rb + lrow) * K + sc * 8;
        dBu[c] = sB + rb * 64;
    }

    for (int s = 0; s < KS; s++) {
        const int k0 = s * 64;
        #pragma unroll
        for (int c = 0; c < AF; c++) async_lds16(ag[c] + k0, dAu[c]);
        #pragma unroll
        for (int c = 0; c < NB; c++) async_lds16(bg[c] + k0, dBu[c]);
        __syncthreads();                          // drain, tile visible
        #pragma unroll
        for (int kc = 0; kc < 2; kc++) {
            bf16x8 af[2], bfr[4];
            #pragma unroll
            for (int t = 0; t < AF; t++) {
                const int row = wm * (16 * AF) + t * 16 + r;
                af[t] = *(const bf16x8*)(sA + row * 64 + ((kc * 4 + quad) ^ (row & 7)) * 8);
            }
            #pragma unroll
            for (int u = 0; u < UN; u++) {
                const int row = wn * (16 * UN) + u * 16 + r;
                bfr[u] = *(const bf16x8*)(sB + row * 64 + ((kc * 4 + quad) ^ (row & 7)) * 8);
            }
            #pragma unroll
            for (int t = 0; t < AF; t++)
                #pragma unroll
                for (int u = 0; u < UN; u++)
                    acc[t][u] = MFMA(af[t], bfr[u], acc[t][u]);
        }
        __syncthreads();                          // protect LDS for next stage
    }
}

// ---------------- fused QKV projection, prep folded in -------------------
// Computes the exact 3-term compensated product [xh|xl|xh] @ [wh|wh|wl]^T
// WITHOUT materializing x_ext/w_ext: each K-step reg-stages the f32 source
// tile, converts hi/lo in-register (bit-identical to prep's split), and
// ds_writes into the same XOR-swizzled LDS layout. 64x64 tiles, grid
// (24,32)=768 blocks (R2-proven occupancy), same 2-barrier step.
__global__ __launch_bounds__(256) void gemm_qkv(
    const float* __restrict__ x,
    const float* __restrict__ wq, const float* __restrict__ wk, const float* __restrict__ wv,
    const float* __restrict__ bq, const float* __restrict__ bk, const float* __restrict__ bv,
    unsigned short* __restrict__ q_ext, unsigned short* __restrict__ k_ext,
    unsigned short* __restrict__ vT)
{
    __shared__ __align__(16) unsigned char smem[64 * 68 * 4];   // 17408 B
    unsigned short* sA = (unsigned short*)smem;                 // 8 KB
    unsigned short* sB = (unsigned short*)(smem + 64 * 64 * 2); // 8 KB
    float* sC = (float*)smem;                                   // 17.4 KB (union)

    const int m0 = blockIdx.y * 64, n0 = blockIdx.x * 64;
    const int tid = threadIdx.x, w = tid >> 6, lane = tid & 63;
    const int quad = lane >> 4, r = lane & 15;
    const int wm = w >> 1, wn = w & 1;
    const int lrow = lane >> 3, lc = lane & 7;
    const int sc = lc ^ lrow;                     // swizzled global chunk

    const int which = n0 >> 9;       // 0:q 1:k 2:v
    const int n0l = n0 & 511;        // = h0*64
    const float* wbase = (which == 0) ? wq : (which == 1) ? wk : wv;

    f32x4 acc[2][4] = {};
    for (int s = 0; s < 24; s++) {
        const int seg = s >> 3;                   // 0,1,2
        const int kk = (s & 7) * 64 + sc * 8;     // f32 k-offset of this chunk
        const bool loA = (seg == 1);              // x row = [xh | xl | xh]
        const bool loB = (seg == 2);              // w row = [wh | wh | wl]
        #pragma unroll
        for (int c = 0; c < 2; c++) {
            const int rb = w * 16 + c * 8;
            const float* src = x + (long)(m0 + rb + lrow) * 512 + kk;
            const float4 v0 = *(const float4*)src;
            const float4 v1 = *(const float4*)(src + 4);
            *(bf16x8*)(sA + (rb + lrow) * 64 + lc * 8) = pack8(v0, v1, loA);
        }
        #pragma unroll
        for (int c = 0; c < 2; c++) {
            const int rb = w * 16 + c * 8;
            const float* src = wbase + (long)(n0l + rb + lrow) * 512 + kk;
            const float4 v0 = *(const float4*)src;
            const float4 v1 = *(const float4*)(src + 4);
            *(bf16x8*)(sB + (rb + lrow) * 64 + lc * 8) = pack8(v0, v1, loB);
        }
        __syncthreads();                          // tile visible
        #pragma unroll
        for (int kc = 0; kc < 2; kc++) {
            bf16x8 af[2], bfr[2];
            #pragma unroll
            for (int t = 0; t < 2; t++) {
                const int row = wm * 32 + t * 16 + r;
                af[t] = *(const bf16x8*)(sA + row * 64 + ((kc * 4 + quad) ^ (row & 7)) * 8);
            }
            #pragma unroll
            for (int u = 0; u < 2; u++) {
                const int row = wn * 32 + u * 16 + r;
                bfr[u] = *(const bf16x8*)(sB + row * 64 + ((kc * 4 + quad) ^ (row & 7)) * 8);
            }
            #pragma unroll
            for (int t = 0; t < 2; t++)
                #pragma unroll
                for (int u = 0; u < 2; u++)
                    acc[t][u] = MFMA(af[t], bfr[u], acc[t][u]);
        }
        __syncthreads();                          // protect LDS for next stage
    }

    // epilogue (R2-verified): acc -> sC union -> q_ext/k_ext/vT
    #pragma unroll
    for (int t = 0; t < 2; t++)
        #pragma unroll
        for (int u = 0; u < 2; u++)
            #pragma unroll
            for (int g = 0; g < 4; g++)
                sC[(wm * 32 + t * 16 + quad * 4 + g) * 68 + wn * 32 + u * 16 + r] = acc[t][u][g];
    __syncthreads();

    const int h0 = n0l >> 6;
    const int b = m0 >> 9, s0 = m0 & 511;

    if (which < 2) {
        const float scl = (which == 0) ? 0.125f : 1.0f;
        const float* bias = (which == 0) ? bq : bk;
        unsigned* dst = (unsigned*)((which == 0) ? q_ext : k_ext);
        #pragma unroll
        for (int seg = 0; seg < 3; seg++) {
            // q_ext row = [hi | lo | hi]; k_ext row = [hi | hi | lo]
            const bool lo = (which == 0) ? (seg == 1) : (seg == 2);
            #pragma unroll
            for (int it = 0; it < 8; it++) {
                const int idx = it * 256 + tid;        // 0..2047
                const int sl = idx >> 5;               // s-row 0..63
                const int jc = idx & 31;               // d pair
                const int nc = jc * 2;
                float v0 = (sC[sl * 68 + nc]     + bias[n0l + nc])     * scl;
                float v1 = (sC[sl * 68 + nc + 1] + bias[n0l + nc + 1]) * scl;
                unsigned short a0 = f2bf(v0), a1 = f2bf(v1);
                if (lo) { a0 = f2bf(v0 - bf2f(a0)); a1 = f2bf(v1 - bf2f(a1)); }
                const long orow = (long)(b * NH + h0) * SEQ + s0 + sl;
                dst[orow * 96 + seg * 32 + jc] = (unsigned)a0 | ((unsigned)a1 << 16);
            }
        }
    } else {
        unsigned* dst = (unsigned*)vT;
        #pragma unroll
        for (int it = 0; it < 8; it++) {
            const int idx = it * 256 + tid;
            const int d = idx >> 5;                    // 0..63
            const int jc = idx & 31;                   // s pair
            const int sl = jc * 2;
            const float bvv = bv[n0l + d];
            const float v0 = sC[sl * 68 + d] + bvv;
            const float v1 = sC[(sl + 1) * 68 + d] + bvv;
            const long orow = (long)(b * NH + h0) * DHD + d;
            dst[orow * 256 + (s0 >> 1) + jc] = (unsigned)f2bf(v0) | ((unsigned)f2bf(v1) << 16);
        }
    }
}

// ---------------- scores = q_ext @ k_ext^T per (b,h), K=192 -> fp16 ------
// Also computes the transform LUT in 9 designated blocks (prep deleted).
__global__ __launch_bounds__(256) void gemm_scores(
    const unsigned short* __restrict__ q_ext, const unsigned short* __restrict__ k_ext,
    const float* __restrict__ w1, const float* __restrict__ b1,
    const float* __restrict__ w2, const float* __restrict__ b2,
    float* __restrict__ lut,
    unsigned short* __restrict__ scoresH)
{
    __shared__ __align__(16) unsigned short sA[64 * 64];
    __shared__ __align__(16) unsigned short sB[128 * 64];
    const int z = blockIdx.z;
    const int m0 = blockIdx.y * 64, n0 = blockIdx.x * 128;

    // LUT prologue: blocks (x==0, y==0, z<9) build lut[0..LUTN] for the
    // transform kernel (next launch). Identical math to old prep_kernel.
    if (blockIdx.x == 0 && blockIdx.y == 0 && z < 9) {
        const int i = z * 256 + threadIdx.x;
        if (i <= LUTN) {
            const float xv = XMIN + i * XSTEP;
            float a = 0.f;
            for (int h = 0; h < HIDN; h++) {
                float hv = xv * w1[h] + b1[h];
                hv = fminf(fmaxf(hv, -5.f), 5.f);
                hv = fmaxf(hv, 0.f);
                a += hv * w2[h];
            }
            a += b2[0];
            a = fminf(fmaxf(a, -5.f), 5.f);
            const float taylor = fminf(fmaxf(1.f + 2.5f * a, 0.5f), 1.5f);
            lut[i] = 1.f / (1.f + expf(-taylor));
        }
    }

    f32x4 acc[2][4] = {};
    gemm_core64<3, 4, 64>(q_ext + (long)z * SEQ * 192, k_ext + (long)z * SEQ * 192,
                          m0, n0, sA, sB, acc);

    const int tid = threadIdx.x, w = tid >> 6, lane = tid & 63;
    const int quad = lane >> 4, r = lane & 15;
    const int wm = w >> 1, wn = w & 1;
    // pack fp16 tile into LDS (reuse sB: 64x128 halves = 16 KB), then 16B stores
    unsigned short* hC = sB;
    #pragma unroll
    for (int t = 0; t < 2; t++)
        #pragma unroll
        for (int u = 0; u < 4; u++)
            #pragma unroll
            for (int g = 0; g < 4; g++) {
                const int ml = wm * 32 + t * 16 + quad * 4 + g;
                const int nl = wn * 64 + u * 16 + r;
                hC[ml * 128 + nl] = ftof16(fminf(fmaxf(acc[t][u][g], -15.f), 15.f));
            }
    __syncthreads();
    #pragma unroll
    for (int it = 0; it < 4; it++) {
        const int id = it * 256 + tid;       // 0..1023
        const int ml = id >> 4, ch = id & 15;
        *(uint4*)(scoresH + ((long)z * SEQ + m0 + ml) * SEQ + n0 + ch * 8) =
            *(const uint4*)(hC + ml * 128 + ch * 8);
    }
}

// ---------------- out = otmp @ wo^T + bo (barrier-free, wo f32 direct) ---
// Both operands L2-hot; wo converted f32->bf16 at load (removes woh build).
__global__ __launch_bounds__(256) void gemm_proj(
    const unsigned short* __restrict__ otmp, const float* __restrict__ wo,
    const float* __restrict__ bo, float* __restrict__ out)
{
    const int m0 = blockIdx.y * 32, n0 = blockIdx.x * 64;
    const int tid = threadIdx.x, w = tid >> 6, lane = tid & 63;
    const int quad = lane >> 4, r = lane & 15;
    const int wm = w >> 1, wn = w & 1;

    const unsigned short* aB = otmp + (long)(m0 + wm * 16 + r) * EMB + quad * 8;
    const float* wB0 = wo + (long)(n0 + wn * 32 + r) * EMB + quad * 8;
    const float* wB1 = wB0 + 16 * EMB;

    f32x4 acc[2] = {};
    #pragma unroll 4
    for (int kc = 0; kc < 16; kc++) {           // K = 512 = 16 x 32
        const int k = kc * 32;
        const bf16x8 a = *(const bf16x8*)(aB + k);
        const bf16x8 b0 = pack8(*(const float4*)(wB0 + k), *(const float4*)(wB0 + k + 4), false);
        const bf16x8 b1 = pack8(*(const float4*)(wB1 + k), *(const float4*)(wB1 + k + 4), false);
        acc[0] = MFMA(a, b0, acc[0]);
        acc[1] = MFMA(a, b1, acc[1]);
    }
    #pragma unroll
    for (int u = 0; u < 2; u++)
        #pragma unroll
        for (int g = 0; g < 4; g++) {
            const int m = m0 + wm * 16 + quad * 4 + g;
            const int n = n0 + wn * 32 + u * 16 + r;
            out[(long)m * EMB + n] = acc[u][g] + bo[n];
        }
}

// ---------------- block reduction helpers (blockDim=256, 4 waves) --------
__device__ __forceinline__ float blockReduceSum(float v, float* sred) {
    #pragma unroll
    for (int o = 32; o > 0; o >>= 1) v += __shfl_down(v, o);
    __syncthreads();
    if ((threadIdx.x & 63) == 0) sred[threadIdx.x >> 6] = v;
    __syncthreads();
    return (sred[0] + sred[1]) + (sred[2] + sred[3]);
}
// packed 4-component sum reduce: one barrier pair instead of four
__device__ __forceinline__ float4 blockReduceSum4(float4 v, float4* s4) {
    #pragma unroll
    for (int o = 32; o > 0; o >>= 1) {
        v.x += __shfl_down(v.x, o); v.y += __shfl_down(v.y, o);
        v.z += __shfl_down(v.z, o); v.w += __shfl_down(v.w, o);
    }
    __syncthreads();
    if ((threadIdx.x & 63) == 0) s4[threadIdx.x >> 6] = v;
    __syncthreads();
    float4 r;
    r.x = (s4[0].x + s4[1].x) + (s4[2].x + s4[3].x);
    r.y = (s4[0].y + s4[1].y) + (s4[2].y + s4[3].y);
    r.z = (s4[0].z + s4[1].z) + (s4[2].z + s4[3].z);
    r.w = (s4[0].w + s4[1].w) + (s4[2].w + s4[3].w);
    return r;
}

// ---------------- transform kernel: one block per (b,i) row (R2-proven) --
__global__ __launch_bounds__(256) void transform_kernel(
    const unsigned short* __restrict__ scoresH, // [B,H,S,S] fp16 (clamped)
    const float* __restrict__ lut,              // [LUTN+1]
    unsigned short* __restrict__ t0H,           // [B,S,S] fp16
    float4* __restrict__ partials)              // [B*S] float4 slots
{
    const int rr = blockIdx.x;
    const int b = rr >> 9, i = rr & 511;
    const int tid = threadIdx.x;

    __shared__ float slut[LUTN + 1];
    __shared__ float sred[4];
    __shared__ float4 sred4[4];

    for (int u = tid; u <= LUTN; u += 256) slut[u] = lut[u];

    // mean over heads: packed fp16 pair loads (j = 2*tid, 2*tid+1)
    const unsigned* baseU =
        (const unsigned*)(scoresH + (((long)(b * NH)) * SEQ + i) * SEQ) + tid;
    float s0 = 0.f, s1 = 0.f;
    #pragma unroll
    for (int h = 0; h < NH; h++) {
        const unsigned pv = baseU[h * (SEQ * SEQ / 2)];
        s0 += f16tof((unsigned short)pv);
        s1 += f16tof((unsigned short)(pv >> 16));
    }
    float mv[2] = { s0 * 0.125f, s1 * 0.125f };
    __syncthreads();

    float sigv[2], ex[2];
    float lsum = 0.f;
    #pragma unroll
    for (int u = 0; u < 2; u++) {
        const float m = mv[u];
        const float x = fminf(fmaxf(m, -8.f), 8.f) * EPSS;
        float t = (x - XMIN) * (1.0f / XSTEP);
        int idx = (int)t;
        idx = idx < 0 ? 0 : (idx > LUTN - 1 ? LUTN - 1 : idx);
        const float frac = t - (float)idx;
        const float l0 = slut[idx], l1 = slut[idx + 1];
        sigv[u] = l0 + frac * (l1 - l0);
        ex[u] = expf(fminf(fmaxf(m, -10.f), 10.f));   // |arg|<=10: safe unshifted
        lsum += ex[u];
    }
    const float rsum = blockReduceSum(lsum, sred);
    const float inv = 1.f / rsum;

    float ex2[2], lsum2 = 0.f;
    #pragma unroll
    for (int u = 0; u < 2; u++) {
        const float p = ex[u] * inv;
        const float he = -p * logf(p + 1e-6f);
        ex2[u] = expf(3.f * he);                      // arg in [0,1.1]: safe
        lsum2 += ex2[u];
    }
    const float rsum2 = blockReduceSum(lsum2, sred);
    const float inv2 = 1.f / rsum2;

    float tv[2];
    #pragma unroll
    for (int u = 0; u < 2; u++) tv[u] = sigv[u] * (ex2[u] * inv2);
    ((unsigned*)t0H)[((long)b * SEQ + i) * (SEQ / 2) + tid] =
        (unsigned)ftof16(tv[0]) | ((unsigned)ftof16(tv[1]) << 16);

    float4 pv;
    pv.x = mv[0] + mv[1];
    pv.y = mv[0] * mv[0] + mv[1] * mv[1];
    pv.z = tv[0] + tv[1];
    pv.w = tv[0] * tv[0] + tv[1] * tv[1];
    const float4 rs = blockReduceSum4(pv, sred4);
    if (tid == 0) partials[rr] = rs;
}

// ---------------- fused coef + softmax + attn@v (R2-proven, 40 KB) -------
__global__ __launch_bounds__(256) void softmax_attnv(
    const unsigned short* __restrict__ scoresH, // [B,H,S,S] fp16
    const unsigned short* __restrict__ t0H,     // [B,S,S] fp16
    const float4* __restrict__ partials,        // [B*S]
    const unsigned short* __restrict__ vT,      // [B,H,DH,S] bf16
    unsigned short* __restrict__ otmp)          // [B*S, E] bf16
{
    __shared__ __align__(16) unsigned char smem[40960];
    unsigned short* attnS = (unsigned short*)smem;            // [32][512] bf16, XOR-swz
    unsigned short* sB    = (unsigned short*)(smem + 32768);  // [64][64] V tile
    float*  sC    = (float*)smem;                             // [32][66] epilogue (union)
    float4* sred4 = (float4*)smem;                            // phase A scratch (union)

    const int m0 = blockIdx.x * 32;
    const int z  = blockIdx.y;
    const int b  = z >> 3, h = z & 7;
    const int tid = threadIdx.x, wv = tid >> 6, lane = tid & 63;

    // --- phase A: coef (redundant per block) ---
    const float4 p0 = partials[b * SEQ + tid];
    const float4 p1 = partials[b * SEQ + tid + 256];
    float4 pv4 = make_float4(p0.x + p1.x, p0.y + p1.y, p0.z + p1.z, p0.w + p1.w);
    const float4 rs4 = blockReduceSum4(pv4, sred4);
    const float sm = rs4.x, sm2 = rs4.y, st = rs4.z, st2 = rs4.w;
    const float n = (float)SEQ * (float)SEQ;
    const float gamma = fminf(fmaxf((sqrtf(sm2) + 1e-4f) / (sqrtf(st2) + 1e-4f), 0.8f), 1.2f);
    const float o_mean = sm / n, t0m = st / n;
    const float o_std = sqrtf(fmaxf(fmaxf(sm2 / n - o_mean * o_mean, 0.f), 0.01f));
    const float t_std = sqrtf(fmaxf(gamma * gamma * fmaxf(st2 / n - t0m * t0m, 0.f), 0.01f));
    const float gdyn = fminf(fmaxf(o_std / t_std, 0.8f), 1.2f);
    const float c1 = gdyn * gamma;
    const float c0 = o_mean - c1 * t0m;
    __syncthreads();   // sred4 reads done before attnS (same bytes) is written

    // V staging: issue step-0 NOW; latency hides under phase B's loads+expf
    const int lrow = lane >> 3, lc = lane & 7;
    const int scw = lc ^ lrow;
    const unsigned short* bg0 = vT + (long)z * DHD * SEQ + (long)(wv * 16 + lrow) * SEQ + scw * 8;
    const unsigned short* bg1 = bg0 + 8 * SEQ;
    unsigned short* dB0 = sB + (wv * 16) * 64;
    unsigned short* dB1 = sB + (wv * 16 + 8) * 64;
    async_lds16(bg0, dB0);
    async_lds16(bg1, dB1);

    // --- phase B: softmax 32 rows -> LDS bf16 tile (unshifted exp: s<=15) ---
    const int j0 = lane * 8;
    for (int it = 0; it < 8; it++) {
        const int rowl = it * 4 + wv;
        const bf16x8 sr = *(const bf16x8*)(scoresH + ((long)z * SEQ + m0 + rowl) * SEQ + j0);
        const bf16x8 tr = *(const bf16x8*)(t0H + ((long)b * SEQ + m0 + rowl) * SEQ + j0);
        float sv[8];
        float lsum = 0.f;
        #pragma unroll
        for (int u = 0; u < 8; u++) {
            float s = f16tof((unsigned short)sr[u])
                    + ALPHA * (c0 + c1 * f16tof((unsigned short)tr[u]));
            s = fminf(fmaxf(s, -15.f), 15.f);
            sv[u] = expf(s);                      // exp(15)=3.3e6: fp32-safe
            lsum += sv[u];
        }
        #pragma unroll
        for (int o = 32; o > 0; o >>= 1) lsum += __shfl_down(lsum, o);
        lsum = __shfl(lsum, 0);
        const float inv = 1.f / lsum;
        bf16x8 pk;
        #pragma unroll
        for (int u = 0; u < 8; u++) pk[u] = (short)f2bf(sv[u] * inv);
        *(bf16x8*)(attnS + rowl * 512 + (j0 ^ ((rowl & 7) << 3))) = pk;
    }

    // --- phase C: attn(LDS) @ vT (single buffer; stage(s+1) post-barrier) ---
    const int quad = lane >> 4, r = lane & 15;
    const int wm = wv >> 1, wn = wv & 1;
    const int arow = wm * 16 + r;
    const int aswz = (arow & 7) << 3;
    f32x4 acc[2] = {};
    for (int s = 0; s < 8; s++) {
        __syncthreads();       // stage(s) drained; s==0 also makes attnS visible
        const int k0 = s * 64;
        #pragma unroll
        for (int kc = 0; kc < 2; kc++) {
            const bf16x8 a = *(const bf16x8*)(attnS + arow * 512 + ((k0 + kc * 32 + quad * 8) ^ aswz));
            #pragma unroll
            for (int u = 0; u < 2; u++) {
                const int row = wn * 32 + u * 16 + r;
                const bf16x8 bb = *(const bf16x8*)(sB + row * 64 + ((kc * 4 + quad) ^ (row & 7)) * 8);
                acc[u] = MFMA(a, bb, acc[u]);
            }
        }
        __syncthreads();       // all waves done reading sB for step s
        if (s < 7) { async_lds16(bg0 + (s + 1) * 64, dB0); async_lds16(bg1 + (s + 1) * 64, dB1); }
    }

    // --- phase D: epilogue (sC overlays attnS; all reads done at last barrier) ---
    #pragma unroll
    for (int u = 0; u < 2; u++)
        #pragma unroll
        for (int g = 0; g < 4; g++)
            sC[(wm * 16 + quad * 4 + g) * 66 + wn * 32 + u * 16 + r] = acc[u][g];
    __syncthreads();
    unsigned* dst = (unsigned*)otmp;
    #pragma unroll
    for (int it = 0; it < 4; it++) {
        const int idx = it * 256 + tid;
        const int sr2 = idx >> 5, jc = idx & 31;
        const float v0 = sC[sr2 * 66 + jc * 2], v1 = sC[sr2 * 66 + jc * 2 + 1];
        dst[((long)(b * SEQ + m0 + sr2)) * 256 + h * 32 + jc] =
            (unsigned)f2bf(v0) | ((unsigned)f2bf(v1) << 16);
    }
}

// -------------------------------------------------------------------------
extern "C" void kernel_launch(void* const* d_in, const int* in_sizes, int n_in,
                              void* d_out, int out_size, void* d_ws, size_t ws_size,
                              hipStream_t stream) {
    const float* x  = (const float*)d_in[0];
    const float* wq = (const float*)d_in[1];
    const float* bq = (const float*)d_in[2];
    const float* wk = (const float*)d_in[3];
    const float* bk = (const float*)d_in[4];
    const float* wv = (const float*)d_in[5];
    const float* bv = (const float*)d_in[6];
    const float* wo = (const float*)d_in[7];
    const float* bo = (const float*)d_in[8];
    const float* w1 = (const float*)d_in[9];
    const float* b1 = (const float*)d_in[10];
    const float* w2 = (const float*)d_in[11];
    const float* b2 = (const float*)d_in[12];
    float* out = (float*)d_out;

    // ---- workspace layout (~34 MB; x_ext/w_ext/woh eliminated) ----
    char* wsb = (char*)d_ws;
    unsigned short* scoresH = (unsigned short*)wsb;        // 16 MB [B,H,S,S] fp16
    unsigned short* t0H     = scoresH + 8388608;           // 2 MB  [B,S,S] fp16
    float4* partials = (float4*)(t0H + 1048576);           // 32 KB
    float*  lutbuf   = (float*)(partials + 2048);
    unsigned short* u16 = (unsigned short*)(wsb + (20u << 20));
    unsigned short* q_ext = u16;                           // 6 MB   [B*H*S,192]
    unsigned short* k_ext = q_ext + 3145728;               // 6 MB
    unsigned short* vT    = k_ext + 3145728;               // 2 MB   [B,H,DH,S]
    unsigned short* otmp  = vT + 1048576;                  // 2 MB   [B*S, E]

    // 1) fused QKV projection (prep folded in: on-the-fly f32->hi/lo split)
    gemm_qkv<<<dim3(24, 32), dim3(256), 0, stream>>>(
        x, wq, wk, wv, bq, bk, bv, q_ext, k_ext, vT);

    // 2) scores = q @ k^T per (b,h) (compensated, K=192) -> fp16; + LUT build
    gemm_scores<<<dim3(4, 8, 32), dim3(256), 0, stream>>>(
        q_ext, k_ext, w1, b1, w2, b2, lutbuf, scoresH);

    // 3) autopoietic transform (LUT-based, 2048 blocks, R2-proven)
    transform_kernel<<<dim3(BATCH * SEQ), dim3(256), 0, stream>>>(
        scoresH, lutbuf, t0H, partials);

    // 4) fused coef + residual/softmax + attn@v (fp16 in, BK=64, 40KB LDS)
    softmax_attnv<<<dim3(16, 32), dim3(256), 0, stream>>>(
        scoresH, t0H, partials, vT, otmp);

    // 5) out = otmp @ wo^T + bo (barrier-free, wo f32 direct, 512 blocks)
    gemm_proj<<<dim3(8, 64), dim3(256), 0, stream>>>(otmp, wo, bo, out);
}

// Round 9
// 155.932 us; speedup vs baseline: 1.1820x; 1.1820x over previous
//
#include <hip/hip_runtime.h>
#include <math.h>

// Problem constants (reference: B=4, S=512, E=512, H=8, DH=64, HID=128)
#define BATCH 4
#define SEQ   512
#define EMB   512
#define NH    8
#define DHD   64
#define HIDN  128
#define ALPHA 0.1f
#define EPSS  0.05f

// LUT for the pointwise conv-chain -> sigmoid function of `scaled`
#define LUTN  2048
#define XMIN  (-0.4f)
#define XSTEP (0.8f / LUTN)

typedef __attribute__((ext_vector_type(8))) short  bf16x8;
typedef __attribute__((ext_vector_type(4))) float  f32x4;
#define MFMA(a,b,c) __builtin_amdgcn_mfma_f32_16x16x32_bf16((a),(b),(c),0,0,0)

__device__ __forceinline__ unsigned short f2bf(float f) {
    union { float f; unsigned u; } v; v.f = f;
    unsigned r = v.u + 0x7fffu + ((v.u >> 16) & 1u);   // RNE; inputs finite
    return (unsigned short)(r >> 16);
}
__device__ __forceinline__ float bf2f(unsigned short h) {
    union { unsigned u; float f; } v; v.u = ((unsigned)h) << 16;
    return v.f;
}
__device__ __forceinline__ float f16tof(unsigned short h) {
    union { unsigned short s; _Float16 f; } v; v.s = h; return (float)v.f;
}
__device__ __forceinline__ unsigned short ftof16(float f) {
    union { unsigned short s; _Float16 f; } v; v.f = (_Float16)f; return v.s;
}

// async global->LDS, 16B per lane; LDS dst = uniform base + lane*16
__device__ __forceinline__ void async_lds16(const unsigned short* g, unsigned short* l) {
    __builtin_amdgcn_global_load_lds(
        (const __attribute__((address_space(1))) void*)g,
        (__attribute__((address_space(3))) void*)l, 16, 0, 0);
}

// ---------------- BK=64 GEMM core (single-buffer, 2 barriers/step) -------
// NT: C[m,n] = sum_k A[m,k]*B[n,k], row-major bf16, K = KS*64.
// 256 thr / 4 waves as 2x2. Latency-bound at this problem size: needs >=3
// co-resident blocks/CU; cross-block wave overlap hides staging latency.
// (R1 dbuf: -9; R3 grid.sync: -546; R5 big tile: -15; R8 prep-fold: -38.)
template<int KS, int UN, int MT>
__device__ __forceinline__ void gemm_core64(
    const unsigned short* __restrict__ A, const unsigned short* __restrict__ B,
    int m0, int n0, unsigned short* sA, unsigned short* sB, f32x4 (&acc)[2][4])
{
    const int K = KS * 64;
    const int tid = threadIdx.x, w = tid >> 6, lane = tid & 63;
    const int quad = lane >> 4, r = lane & 15;
    const int wm = w >> 1, wn = w & 1;
    const int lrow = lane >> 3, lc = lane & 7;
    const int sc = lc ^ lrow;                     // swizzled global chunk
    constexpr int AF = MT / 32;                   // A frags per wave
    constexpr int NB = UN;                        // B staging calls per wave

    const unsigned short* ag[2]; unsigned short* dAu[2];
    #pragma unroll
    for (int c = 0; c < AF; c++) {
        const int rb = w * (8 * AF) + c * 8;
        ag[c]  = A + (long)(m0 + rb + lrow) * K + sc * 8;
        dAu[c] = sA + rb * 64;
    }
    const unsigned short* bg[4]; unsigned short* dBu[4];
    #pragma unroll
    for (int c = 0; c < NB; c++) {
        const int rb = w * (8 * NB) + c * 8;
        bg[c]  = B + (long)(n0 + rb + lrow) * K + sc * 8;
        dBu[c] = sB + rb * 64;
    }

    for (int s = 0; s < KS; s++) {
        const int k0 = s * 64;
        #pragma unroll
        for (int c = 0; c < AF; c++) async_lds16(ag[c] + k0, dAu[c]);
        #pragma unroll
        for (int c = 0; c < NB; c++) async_lds16(bg[c] + k0, dBu[c]);
        __syncthreads();                          // drain, tile visible
        #pragma unroll
        for (int kc = 0; kc < 2; kc++) {
            bf16x8 af[2], bfr[4];
            #pragma unroll
            for (int t = 0; t < AF; t++) {
                const int row = wm * (16 * AF) + t * 16 + r;
                af[t] = *(const bf16x8*)(sA + row * 64 + ((kc * 4 + quad) ^ (row & 7)) * 8);
            }
            #pragma unroll
            for (int u = 0; u < UN; u++) {
                const int row = wn * (16 * UN) + u * 16 + r;
                bfr[u] = *(const bf16x8*)(sB + row * 64 + ((kc * 4 + quad) ^ (row & 7)) * 8);
            }
            #pragma unroll
            for (int t = 0; t < AF; t++)
                #pragma unroll
                for (int u = 0; u < UN; u++)
                    acc[t][u] = MFMA(af[t], bfr[u], acc[t][u]);
        }
        __syncthreads();                          // protect LDS for next stage
    }
}

// ---------------- fused QKV projection (R2-proven: 64x64, 768 blocks) ----
__global__ __launch_bounds__(256) void gemm_qkv(
    const unsigned short* __restrict__ x_ext, const unsigned short* __restrict__ w_ext,
    const float* __restrict__ bq, const float* __restrict__ bk, const float* __restrict__ bv,
    unsigned short* __restrict__ q_ext, unsigned short* __restrict__ k_ext,
    unsigned short* __restrict__ vT)
{
    __shared__ __align__(16) unsigned char smem[64 * 68 * 4];   // 17408 B
    unsigned short* sA = (unsigned short*)smem;                 // 8 KB
    unsigned short* sB = (unsigned short*)(smem + 64 * 64 * 2); // 8 KB
    float* sC = (float*)smem;                                   // 17.4 KB (union)

    const int m0 = blockIdx.y * 64, n0 = blockIdx.x * 64;
    f32x4 acc[2][4] = {};
    gemm_core64<24, 2, 64>(x_ext, w_ext, m0, n0, sA, sB, acc);

    const int tid = threadIdx.x, w = tid >> 6, lane = tid & 63;
    const int quad = lane >> 4, r = lane & 15;
    const int wm = w >> 1, wn = w & 1;
    #pragma unroll
    for (int t = 0; t < 2; t++)
        #pragma unroll
        for (int u = 0; u < 2; u++)
            #pragma unroll
            for (int g = 0; g < 4; g++)
                sC[(wm * 32 + t * 16 + quad * 4 + g) * 68 + wn * 32 + u * 16 + r] = acc[t][u][g];
    __syncthreads();

    const int which = n0 >> 9;       // 0:q 1:k 2:v
    const int n0l = n0 & 511;        // = h0*64
    const int h0 = n0l >> 6;
    const int b = m0 >> 9, s0 = m0 & 511;

    if (which < 2) {
        const float scl = (which == 0) ? 0.125f : 1.0f;
        const float* bias = (which == 0) ? bq : bk;
        unsigned* dst = (unsigned*)((which == 0) ? q_ext : k_ext);
        #pragma unroll
        for (int seg = 0; seg < 3; seg++) {
            // q_ext row = [hi | lo | hi]; k_ext row = [hi | hi | lo]
            const bool lo = (which == 0) ? (seg == 1) : (seg == 2);
            #pragma unroll
            for (int it = 0; it < 8; it++) {
                const int idx = it * 256 + tid;        // 0..2047
                const int sl = idx >> 5;               // s-row 0..63
                const int jc = idx & 31;               // d pair
                const int nc = jc * 2;
                float v0 = (sC[sl * 68 + nc]     + bias[n0l + nc])     * scl;
                float v1 = (sC[sl * 68 + nc + 1] + bias[n0l + nc + 1]) * scl;
                unsigned short a0 = f2bf(v0), a1 = f2bf(v1);
                if (lo) { a0 = f2bf(v0 - bf2f(a0)); a1 = f2bf(v1 - bf2f(a1)); }
                const long orow = (long)(b * NH + h0) * SEQ + s0 + sl;
                dst[orow * 96 + seg * 32 + jc] = (unsigned)a0 | ((unsigned)a1 << 16);
            }
        }
    } else {
        unsigned* dst = (unsigned*)vT;
        #pragma unroll
        for (int it = 0; it < 8; it++) {
            const int idx = it * 256 + tid;
            const int d = idx >> 5;                    // 0..63
            const int jc = idx & 31;                   // s pair
            const int sl = jc * 2;
            const float bvv = bv[n0l + d];
            const float v0 = sC[sl * 68 + d] + bvv;
            const float v1 = sC[(sl + 1) * 68 + d] + bvv;
            const long orow = (long)(b * NH + h0) * DHD + d;
            dst[orow * 256 + (s0 >> 1) + jc] = (unsigned)f2bf(v0) | ((unsigned)f2bf(v1) << 16);
        }
    }
}

// ---------------- scores = q_ext @ k_ext^T per (b,h), K=192 -> fp16 ------
__global__ __launch_bounds__(256) void gemm_scores(
    const unsigned short* __restrict__ q_ext, const unsigned short* __restrict__ k_ext,
    unsigned short* __restrict__ scoresH)
{
    __shared__ __align__(16) unsigned short sA[64 * 64];
    __shared__ __align__(16) unsigned short sB[128 * 64];
    const int z = blockIdx.z;
    const int m0 = blockIdx.y * 64, n0 = blockIdx.x * 128;
    f32x4 acc[2][4] = {};
    gemm_core64<3, 4, 64>(q_ext + (long)z * SEQ * 192, k_ext + (long)z * SEQ * 192,
                          m0, n0, sA, sB, acc);

    const int tid = threadIdx.x, w = tid >> 6, lane = tid & 63;
    const int quad = lane >> 4, r = lane & 15;
    const int wm = w >> 1, wn = w & 1;
    // pack fp16 tile into LDS (reuse sB: 64x128 halves = 16 KB), then 16B stores
    unsigned short* hC = sB;
    #pragma unroll
    for (int t = 0; t < 2; t++)
        #pragma unroll
        for (int u = 0; u < 4; u++)
            #pragma unroll
            for (int g = 0; g < 4; g++) {
                const int ml = wm * 32 + t * 16 + quad * 4 + g;
                const int nl = wn * 64 + u * 16 + r;
                hC[ml * 128 + nl] = ftof16(fminf(fmaxf(acc[t][u][g], -15.f), 15.f));
            }
    __syncthreads();
    #pragma unroll
    for (int it = 0; it < 4; it++) {
        const int id = it * 256 + tid;       // 0..1023
        const int ml = id >> 4, ch = id & 15;
        *(uint4*)(scoresH + ((long)z * SEQ + m0 + ml) * SEQ + n0 + ch * 8) =
            *(const uint4*)(hC + ml * 128 + ch * 8);
    }
}

// ---------------- out = otmp @ woh^T + bo (barrier-free, LDS-free) -------
// Both operands L2-hot (otmp 2 MB, woh 0.5 MB): fragments loaded directly
// from global, zero __syncthreads; same grid (8,64)=512 blocks as R2.
__global__ __launch_bounds__(256) void gemm_proj(
    const unsigned short* __restrict__ otmp, const unsigned short* __restrict__ woh,
    const float* __restrict__ bo, float* __restrict__ out)
{
    const int m0 = blockIdx.y * 32, n0 = blockIdx.x * 64;
    const int tid = threadIdx.x, w = tid >> 6, lane = tid & 63;
    const int quad = lane >> 4, r = lane & 15;
    const int wm = w >> 1, wn = w & 1;

    const unsigned short* aB = otmp + (long)(m0 + wm * 16 + r) * EMB + quad * 8;
    const unsigned short* bB0 = woh + (long)(n0 + wn * 32 + r) * EMB + quad * 8;
    const unsigned short* bB1 = bB0 + 16 * EMB;

    f32x4 acc[2] = {};
    #pragma unroll 4
    for (int kc = 0; kc < 16; kc++) {           // K = 512 = 16 x 32
        const int k = kc * 32;
        const bf16x8 a  = *(const bf16x8*)(aB + k);
        const bf16x8 b0 = *(const bf16x8*)(bB0 + k);
        const bf16x8 b1 = *(const bf16x8*)(bB1 + k);
        acc[0] = MFMA(a, b0, acc[0]);
        acc[1] = MFMA(a, b1, acc[1]);
    }
    #pragma unroll
    for (int u = 0; u < 2; u++)
        #pragma unroll
        for (int g = 0; g < 4; g++) {
            const int m = m0 + wm * 16 + quad * 4 + g;
            const int n = n0 + wn * 32 + u * 16 + r;
            out[(long)m * EMB + n] = acc[u][g] + bo[n];
        }
}

// ---------------- block reduction helpers (blockDim=256, 4 waves) --------
__device__ __forceinline__ float blockReduceSum(float v, float* sred) {
    #pragma unroll
    for (int o = 32; o > 0; o >>= 1) v += __shfl_down(v, o);
    __syncthreads();
    if ((threadIdx.x & 63) == 0) sred[threadIdx.x >> 6] = v;
    __syncthreads();
    return (sred[0] + sred[1]) + (sred[2] + sred[3]);
}
// packed 4-component sum reduce: one barrier pair instead of four
__device__ __forceinline__ float4 blockReduceSum4(float4 v, float4* s4) {
    #pragma unroll
    for (int o = 32; o > 0; o >>= 1) {
        v.x += __shfl_down(v.x, o); v.y += __shfl_down(v.y, o);
        v.z += __shfl_down(v.z, o); v.w += __shfl_down(v.w, o);
    }
    __syncthreads();
    if ((threadIdx.x & 63) == 0) s4[threadIdx.x >> 6] = v;
    __syncthreads();
    float4 r;
    r.x = (s4[0].x + s4[1].x) + (s4[2].x + s4[3].x);
    r.y = (s4[0].y + s4[1].y) + (s4[2].y + s4[3].y);
    r.z = (s4[0].z + s4[1].z) + (s4[2].z + s4[3].z);
    r.w = (s4[0].w + s4[1].w) + (s4[2].w + s4[3].w);
    return r;
}

// ---------------- fused prep: LUT + ext-K split builds (float4) ----------
__global__ __launch_bounds__(256) void prep_kernel(
    const float* __restrict__ x,
    const float* __restrict__ wq, const float* __restrict__ wk,
    const float* __restrict__ wv, const float* __restrict__ wo,
    const float* __restrict__ w1, const float* __restrict__ b1,
    const float* __restrict__ w2, const float* __restrict__ b2,
    unsigned short* __restrict__ x_ext, unsigned short* __restrict__ w_ext,
    unsigned short* __restrict__ woh, float* __restrict__ lut)
{
    const int blk = blockIdx.x;
    if (blk < 9) {
        const int i = blk * 256 + threadIdx.x;
        if (i > LUTN) return;
        const float xv = XMIN + i * XSTEP;
        float a = 0.f;
        for (int h = 0; h < HIDN; h++) {
            float hv = xv * w1[h] + b1[h];
            hv = fminf(fmaxf(hv, -5.f), 5.f);
            hv = fmaxf(hv, 0.f);
            a += hv * w2[h];
        }
        a += b2[0];
        a = fminf(fmaxf(a, -5.f), 5.f);
        const float taylor = fminf(fmaxf(1.f + 2.5f * a, 0.5f), 1.5f);
        lut[i] = 1.f / (1.f + expf(-taylor));
        return;
    }
    const int i = (blk - 9) * 256 + threadIdx.x;   // quad index, 0..524287
    if (i < 262144) {
        // x path: row m (512 floats = 128 quads) -> x_ext row [xh|xl|xh]
        const int m = i >> 7, kq = i & 127;
        const float4 v = ((const float4*)x)[i];
        const unsigned short h0 = f2bf(v.x), h1 = f2bf(v.y), h2 = f2bf(v.z), h3 = f2bf(v.w);
        const unsigned hi01 = (unsigned)h0 | ((unsigned)h1 << 16);
        const unsigned hi23 = (unsigned)h2 | ((unsigned)h3 << 16);
        const unsigned lo01 = (unsigned)f2bf(v.x - bf2f(h0)) | ((unsigned)f2bf(v.y - bf2f(h1)) << 16);
        const unsigned lo23 = (unsigned)f2bf(v.z - bf2f(h2)) | ((unsigned)f2bf(v.w - bf2f(h3)) << 16);
        unsigned* dst = (unsigned*)x_ext;
        const long base = (long)m * 768 + kq * 2;
        dst[base] = hi01;       dst[base + 1] = hi23;       // xh
        dst[base + 256] = lo01; dst[base + 257] = lo23;     // xl
        dst[base + 512] = hi01; dst[base + 513] = hi23;     // xh
    } else if (i < 458752) {
        // w path: row n of stacked [wq;wk;wv] -> w_ext row [wh|wh|wl]
        const int j = i - 262144;                   // 0..196607
        const int n = j >> 7, kq = j & 127;
        const float4 v = (j < 65536) ? ((const float4*)wq)[j]
                       : (j < 131072 ? ((const float4*)wk)[j - 65536]
                                     : ((const float4*)wv)[j - 131072]);
        const unsigned short h0 = f2bf(v.x), h1 = f2bf(v.y), h2 = f2bf(v.z), h3 = f2bf(v.w);
        const unsigned hi01 = (unsigned)h0 | ((unsigned)h1 << 16);
        const unsigned hi23 = (unsigned)h2 | ((unsigned)h3 << 16);
        const unsigned lo01 = (unsigned)f2bf(v.x - bf2f(h0)) | ((unsigned)f2bf(v.y - bf2f(h1)) << 16);
        const unsigned lo23 = (unsigned)f2bf(v.z - bf2f(h2)) | ((unsigned)f2bf(v.w - bf2f(h3)) << 16);
        unsigned* dst = (unsigned*)w_ext;
        const long base = (long)n * 768 + kq * 2;
        dst[base] = hi01;       dst[base + 1] = hi23;       // wh
        dst[base + 256] = hi01; dst[base + 257] = hi23;     // wh
        dst[base + 512] = lo01; dst[base + 513] = lo23;     // wl
    } else {
        const int j = i - 458752;                   // 0..65535
        const float4 v = ((const float4*)wo)[j];
        unsigned* dst = (unsigned*)woh;
        dst[j * 2]     = (unsigned)f2bf(v.x) | ((unsigned)f2bf(v.y) << 16);
        dst[j * 2 + 1] = (unsigned)f2bf(v.z) | ((unsigned)f2bf(v.w) << 16);
    }
}

// ---------------- transform kernel: one block per (b,i) row (R2-proven) --
// Max-subtractions removed: mean-attn clamped to [-10,10] and entropy term
// in [0,1.1], so unshifted expf is fp32-safe -> 2 fewer reduce rounds.
__global__ __launch_bounds__(256) void transform_kernel(
    const unsigned short* __restrict__ scoresH, // [B,H,S,S] fp16 (clamped)
    const float* __restrict__ lut,              // [LUTN+1]
    unsigned short* __restrict__ t0H,           // [B,S,S] fp16
    float4* __restrict__ partials)              // [B*S] float4 slots
{
    const int rr = blockIdx.x;
    const int b = rr >> 9, i = rr & 511;
    const int tid = threadIdx.x;

    __shared__ float slut[LUTN + 1];
    __shared__ float sred[4];
    __shared__ float4 sred4[4];

    for (int u = tid; u <= LUTN; u += 256) slut[u] = lut[u];

    // mean over heads: packed fp16 pair loads (j = 2*tid, 2*tid+1)
    const unsigned* baseU =
        (const unsigned*)(scoresH + (((long)(b * NH)) * SEQ + i) * SEQ) + tid;
    float s0 = 0.f, s1 = 0.f;
    #pragma unroll
    for (int h = 0; h < NH; h++) {
        const unsigned pv = baseU[h * (SEQ * SEQ / 2)];
        s0 += f16tof((unsigned short)pv);
        s1 += f16tof((unsigned short)(pv >> 16));
    }
    float mv[2] = { s0 * 0.125f, s1 * 0.125f };
    __syncthreads();

    float sigv[2], ex[2];
    float lsum = 0.f;
    #pragma unroll
    for (int u = 0; u < 2; u++) {
        const float m = mv[u];
        const float x = fminf(fmaxf(m, -8.f), 8.f) * EPSS;
        float t = (x - XMIN) * (1.0f / XSTEP);
        int idx = (int)t;
        idx = idx < 0 ? 0 : (idx > LUTN - 1 ? LUTN - 1 : idx);
        const float frac = t - (float)idx;
        const float l0 = slut[idx], l1 = slut[idx + 1];
        sigv[u] = l0 + frac * (l1 - l0);
        ex[u] = expf(fminf(fmaxf(m, -10.f), 10.f));   // |arg|<=10: safe unshifted
        lsum += ex[u];
    }
    const float rsum = blockReduceSum(lsum, sred);
    const float inv = 1.f / rsum;

    float ex2[2], lsum2 = 0.f;
    #pragma unroll
    for (int u = 0; u < 2; u++) {
        const float p = ex[u] * inv;
        const float he = -p * logf(p + 1e-6f);
        ex2[u] = expf(3.f * he);                      // arg in [0,1.1]: safe
        lsum2 += ex2[u];
    }
    const float rsum2 = blockReduceSum(lsum2, sred);
    const float inv2 = 1.f / rsum2;

    float tv[2];
    #pragma unroll
    for (int u = 0; u < 2; u++) tv[u] = sigv[u] * (ex2[u] * inv2);
    ((unsigned*)t0H)[((long)b * SEQ + i) * (SEQ / 2) + tid] =
        (unsigned)ftof16(tv[0]) | ((unsigned)ftof16(tv[1]) << 16);

    float4 pv;
    pv.x = mv[0] + mv[1];
    pv.y = mv[0] * mv[0] + mv[1] * mv[1];
    pv.z = tv[0] + tv[1];
    pv.w = tv[0] * tv[0] + tv[1] * tv[1];
    const float4 rs = blockReduceSum4(pv, sred4);
    if (tid == 0) partials[rr] = rs;
}

// ---------------- fused coef + softmax + attn@v --------------------------
// Grid (16 m-tiles of 32 rows, 32 z=(b,h)). Phase C loads V fragments
// DIRECTLY from global (vT = 64 KB/head, L2-resident; staging + 16 K-loop
// barriers were overhead — R6 counter evidence). Barriers: 5, was 21.
// Phases A/B/D byte-identical to the R2-verified kernel.
__global__ __launch_bounds__(256) void softmax_attnv(
    const unsigned short* __restrict__ scoresH, // [B,H,S,S] fp16
    const unsigned short* __restrict__ t0H,     // [B,S,S] fp16
    const float4* __restrict__ partials,        // [B*S]
    const unsigned short* __restrict__ vT,      // [B,H,DH,S] bf16
    unsigned short* __restrict__ otmp)          // [B*S, E] bf16
{
    __shared__ __align__(16) unsigned char smem[32768];
    unsigned short* attnS = (unsigned short*)smem;   // [32][512] bf16, XOR-swz
    float*  sC    = (float*)smem;                    // [32][66] epilogue (union)
    float4* sred4 = (float4*)smem;                   // phase A scratch (union)

    const int m0 = blockIdx.x * 32;
    const int z  = blockIdx.y;
    const int b  = z >> 3, h = z & 7;
    const int tid = threadIdx.x, wv = tid >> 6, lane = tid & 63;

    // --- phase A: coef (redundant per block) ---
    const float4 p0 = partials[b * SEQ + tid];
    const float4 p1 = partials[b * SEQ + tid + 256];
    float4 pv4 = make_float4(p0.x + p1.x, p0.y + p1.y, p0.z + p1.z, p0.w + p1.w);
    const float4 rs4 = blockReduceSum4(pv4, sred4);
    const float sm = rs4.x, sm2 = rs4.y, st = rs4.z, st2 = rs4.w;
    const float n = (float)SEQ * (float)SEQ;
    const float gamma = fminf(fmaxf((sqrtf(sm2) + 1e-4f) / (sqrtf(st2) + 1e-4f), 0.8f), 1.2f);
    const float o_mean = sm / n, t0m = st / n;
    const float o_std = sqrtf(fmaxf(fmaxf(sm2 / n - o_mean * o_mean, 0.f), 0.01f));
    const float t_std = sqrtf(fmaxf(gamma * gamma * fmaxf(st2 / n - t0m * t0m, 0.f), 0.01f));
    const float gdyn = fminf(fmaxf(o_std / t_std, 0.8f), 1.2f);
    const float c1 = gdyn * gamma;
    const float c0 = o_mean - c1 * t0m;
    __syncthreads();   // sred4 reads done before attnS (same bytes) is written

    // --- phase B: softmax 32 rows -> LDS bf16 tile (unshifted exp: s<=15) ---
    const int j0 = lane * 8;
    for (int it = 0; it < 8; it++) {
        const int rowl = it * 4 + wv;
        const bf16x8 sr = *(const bf16x8*)(scoresH + ((long)z * SEQ + m0 + rowl) * SEQ + j0);
        const bf16x8 tr = *(const bf16x8*)(t0H + ((long)b * SEQ + m0 + rowl) * SEQ + j0);
        float sv[8];
        float lsum = 0.f;
        #pragma unroll
        for (int u = 0; u < 8; u++) {
            float s = f16tof((unsigned short)sr[u])
                    + ALPHA * (c0 + c1 * f16tof((unsigned short)tr[u]));
            s = fminf(fmaxf(s, -15.f), 15.f);
            sv[u] = expf(s);                      // exp(15)=3.3e6: fp32-safe
            lsum += sv[u];
        }
        #pragma unroll
        for (int o = 32; o > 0; o >>= 1) lsum += __shfl_down(lsum, o);
        lsum = __shfl(lsum, 0);
        const float inv = 1.f / lsum;
        bf16x8 pk;
        #pragma unroll
        for (int u = 0; u < 8; u++) pk[u] = (short)f2bf(sv[u] * inv);
        *(bf16x8*)(attnS + rowl * 512 + (j0 ^ ((rowl & 7) << 3))) = pk;
    }
    __syncthreads();   // attnS complete (phase C reads rows written by other waves)

    // --- phase C: attn(LDS) @ vT(global direct) — ZERO barriers ----------
    const int quad = lane >> 4, r = lane & 15;
    const int wm = wv >> 1, wn = wv & 1;
    const int arow = wm * 16 + r;
    const int aswz = (arow & 7) << 3;
    const unsigned short* vB0 = vT + (long)z * DHD * SEQ + (long)(wn * 32 + r) * SEQ + quad * 8;
    const unsigned short* vB1 = vB0 + 16 * SEQ;
    f32x4 acc[2] = {};
    #pragma unroll 2
    for (int s = 0; s < 8; s++) {
        const int k0 = s * 64;
        #pragma unroll
        for (int kc = 0; kc < 2; kc++) {
            const int k = k0 + kc * 32;
            const bf16x8 a  = *(const bf16x8*)(attnS + arow * 512 + ((k + quad * 8) ^ aswz));
            const bf16x8 b0 = *(const bf16x8*)(vB0 + k);
            const bf16x8 b1 = *(const bf16x8*)(vB1 + k);
            acc[0] = MFMA(a, b0, acc[0]);
            acc[1] = MFMA(a, b1, acc[1]);
        }
    }
    __syncthreads();   // all waves done reading attnS before sC overlay

    // --- phase D: epilogue (sC overlays attnS) ---
    #pragma unroll
    for (int u = 0; u < 2; u++)
        #pragma unroll
        for (int g = 0; g < 4; g++)
            sC[(wm * 16 + quad * 4 + g) * 66 + wn * 32 + u * 16 + r] = acc[u][g];
    __syncthreads();
    unsigned* dst = (unsigned*)otmp;
    #pragma unroll
    for (int it = 0; it < 4; it++) {
        const int idx = it * 256 + tid;
        const int sr2 = idx >> 5, jc = idx & 31;
        const float v0 = sC[sr2 * 66 + jc * 2], v1 = sC[sr2 * 66 + jc * 2 + 1];
        dst[((long)(b * SEQ + m0 + sr2)) * 256 + h * 32 + jc] =
            (unsigned)f2bf(v0) | ((unsigned)f2bf(v1) << 16);
    }
}

// -------------------------------------------------------------------------
extern "C" void kernel_launch(void* const* d_in, const int* in_sizes, int n_in,
                              void* d_out, int out_size, void* d_ws, size_t ws_size,
                              hipStream_t stream) {
    const float* x  = (const float*)d_in[0];
    const float* wq = (const float*)d_in[1];
    const float* bq = (const float*)d_in[2];
    const float* wk = (const float*)d_in[3];
    const float* bk = (const float*)d_in[4];
    const float* wv = (const float*)d_in[5];
    const float* bv = (const float*)d_in[6];
    const float* wo = (const float*)d_in[7];
    const float* bo = (const float*)d_in[8];
    const float* w1 = (const float*)d_in[9];
    const float* b1 = (const float*)d_in[10];
    const float* w2 = (const float*)d_in[11];
    const float* b2 = (const float*)d_in[12];
    float* out = (float*)d_out;

    // ---- workspace layout (~48 MB) ----
    char* wsb = (char*)d_ws;
    unsigned short* scoresH = (unsigned short*)wsb;        // 16 MB [B,H,S,S] fp16
    unsigned short* t0H     = scoresH + 8388608;           // 2 MB  [B,S,S] fp16
    float4* partials = (float4*)(t0H + 1048576);           // 32 KB
    float*  lutbuf   = (float*)(partials + 2048);
    unsigned short* u16 = (unsigned short*)(wsb + (20u << 20));
    unsigned short* x_ext = u16;                           // 6 MB   [2048,1536]
    unsigned short* w_ext = x_ext + 3145728;               // 4.5 MB [1536,1536]
    unsigned short* q_ext = w_ext + 2359296;               // 6 MB   [B*H*S,192]
    unsigned short* k_ext = q_ext + 3145728;               // 6 MB
    unsigned short* vT    = k_ext + 3145728;               // 2 MB   [B,H,DH,S]
    unsigned short* otmp  = vT + 1048576;                  // 2 MB   [B*S, E]
    unsigned short* woh   = otmp + 1048576;                // 0.5 MB [E,E]

    // 1) prep: LUT + ext-K split builds (float4-vectorized)
    prep_kernel<<<dim3(9 + 2048), dim3(256), 0, stream>>>(
        x, wq, wk, wv, wo, w1, b1, w2, b2, x_ext, w_ext, woh, lutbuf);

    // 2) fused QKV projection (compensated bf16, K=1536, 64x64, 768 blocks)
    gemm_qkv<<<dim3(24, 32), dim3(256), 0, stream>>>(
        x_ext, w_ext, bq, bk, bv, q_ext, k_ext, vT);

    // 3) scores = q @ k^T per (b,h) (compensated, K=192) -> fp16, clamp
    gemm_scores<<<dim3(4, 8, 32), dim3(256), 0, stream>>>(q_ext, k_ext, scoresH);

    // 4) autopoietic transform (LUT-based, 2048 blocks, R2-proven)
    transform_kernel<<<dim3(BATCH * SEQ), dim3(256), 0, stream>>>(
        scoresH, lutbuf, t0H, partials);

    // 5) fused coef + softmax + attn@v (V direct-global, 5 barriers)
    softmax_attnv<<<dim3(16, 32), dim3(256), 0, stream>>>(
        scoresH, t0H, partials, vT, otmp);

    // 6) out = otmp @ woh^T + bo (barrier-free, LDS-free, 512 blocks)
    gemm_proj<<<dim3(8, 64), dim3(256), 0, stream>>>(otmp, woh, bo, out);
}

// Round 10
// 145.193 us; speedup vs baseline: 1.2694x; 1.0740x over previous
//
#include <hip/hip_runtime.h>
#include <math.h>

// Problem constants (reference: B=4, S=512, E=512, H=8, DH=64, HID=128)
#define BATCH 4
#define SEQ   512
#define EMB   512
#define NH    8
#define DHD   64
#define HIDN  128
#define ALPHA 0.1f
#define EPSS  0.05f

// LUT for the pointwise conv-chain -> sigmoid function of `scaled`
#define LUTN  2048
#define XMIN  (-0.4f)
#define XSTEP (0.8f / LUTN)

typedef __attribute__((ext_vector_type(8))) short  bf16x8;
typedef __attribute__((ext_vector_type(4))) float  f32x4;
#define MFMA(a,b,c) __builtin_amdgcn_mfma_f32_16x16x32_bf16((a),(b),(c),0,0,0)

__device__ __forceinline__ unsigned short f2bf(float f) {
    union { float f; unsigned u; } v; v.f = f;
    unsigned r = v.u + 0x7fffu + ((v.u >> 16) & 1u);   // RNE; inputs finite
    return (unsigned short)(r >> 16);
}
__device__ __forceinline__ float bf2f(unsigned short h) {
    union { unsigned u; float f; } v; v.u = ((unsigned)h) << 16;
    return v.f;
}
__device__ __forceinline__ float f16tof(unsigned short h) {
    union { unsigned short s; _Float16 f; } v; v.s = h; return (float)v.f;
}
__device__ __forceinline__ unsigned short ftof16(float f) {
    union { unsigned short s; _Float16 f; } v; v.f = (_Float16)f; return v.s;
}

// async global->LDS, 16B per lane; LDS dst = uniform base + lane*16
__device__ __forceinline__ void async_lds16(const unsigned short* g, unsigned short* l) {
    __builtin_amdgcn_global_load_lds(
        (const __attribute__((address_space(1))) void*)g,
        (__attribute__((address_space(3))) void*)l, 16, 0, 0);
}

// ---------------- BK=64 GEMM core (single-buffer, 2 barriers/step) -------
// NT: C[m,n] = sum_k A[m,k]*B[n,k], row-major bf16, K = KS*64.
// 256 thr / 4 waves as 2x2. MT=64: wave 32 x UN*16; MT=32: wave 16 x UN*16.
// Cross-block wave overlap (3-8 blocks/CU) hides the staging latency.
// Session evidence: R1 dbuf -9, R3 grid.sync -546, R5 128^2 tile -15,
// R6 atomic split-K -29, R7/R9 direct-V -10, R8 prep-fold -38.
template<int KS, int UN, int MT>
__device__ __forceinline__ void gemm_core64(
    const unsigned short* __restrict__ A, const unsigned short* __restrict__ B,
    int m0, int n0, unsigned short* sA, unsigned short* sB, f32x4 (&acc)[2][4])
{
    const int K = KS * 64;
    const int tid = threadIdx.x, w = tid >> 6, lane = tid & 63;
    const int quad = lane >> 4, r = lane & 15;
    const int wm = w >> 1, wn = w & 1;
    const int lrow = lane >> 3, lc = lane & 7;
    const int sc = lc ^ lrow;                     // swizzled global chunk
    constexpr int AF = MT / 32;                   // A frags per wave
    constexpr int NB = UN;                        // B staging calls per wave

    const unsigned short* ag[2]; unsigned short* dAu[2];
    #pragma unroll
    for (int c = 0; c < AF; c++) {
        const int rb = w * (8 * AF) + c * 8;
        ag[c]  = A + (long)(m0 + rb + lrow) * K + sc * 8;
        dAu[c] = sA + rb * 64;
    }
    const unsigned short* bg[4]; unsigned short* dBu[4];
    #pragma unroll
    for (int c = 0; c < NB; c++) {
        const int rb = w * (8 * NB) + c * 8;
        bg[c]  = B + (long)(n0 + rb + lrow) * K + sc * 8;
        dBu[c] = sB + rb * 64;
    }

    for (int s = 0; s < KS; s++) {
        const int k0 = s * 64;
        #pragma unroll
        for (int c = 0; c < AF; c++) async_lds16(ag[c] + k0, dAu[c]);
        #pragma unroll
        for (int c = 0; c < NB; c++) async_lds16(bg[c] + k0, dBu[c]);
        __syncthreads();                          // drain, tile visible
        #pragma unroll
        for (int kc = 0; kc < 2; kc++) {
            bf16x8 af[2], bfr[4];
            #pragma unroll
            for (int t = 0; t < AF; t++) {
                const int row = wm * (16 * AF) + t * 16 + r;
                af[t] = *(const bf16x8*)(sA + row * 64 + ((kc * 4 + quad) ^ (row & 7)) * 8);
            }
            #pragma unroll
            for (int u = 0; u < UN; u++) {
                const int row = wn * (16 * UN) + u * 16 + r;
                bfr[u] = *(const bf16x8*)(sB + row * 64 + ((kc * 4 + quad) ^ (row & 7)) * 8);
            }
            #pragma unroll
            for (int t = 0; t < AF; t++)
                #pragma unroll
                for (int u = 0; u < UN; u++)
                    acc[t][u] = MFMA(af[t], bfr[u], acc[t][u]);
        }
        __syncthreads();                          // protect LDS for next stage
    }
}

// ---------------- fused QKV projection -----------------------------------
// A = x_ext [2048,1536]=[xh|xl|xh]; B = w_ext [1536,1536]=[wh|wh|wl]
// -> exact 3-term compensated product. 64x64 tiles, grid (24,32).
// LDS: sC unioned over sA+sB (epilogue strictly after core's final barrier)
// -> 17.4 KB total.
__global__ __launch_bounds__(256) void gemm_qkv(
    const unsigned short* __restrict__ x_ext, const unsigned short* __restrict__ w_ext,
    const float* __restrict__ bq, const float* __restrict__ bk, const float* __restrict__ bv,
    unsigned short* __restrict__ q_ext, unsigned short* __restrict__ k_ext,
    unsigned short* __restrict__ vT)
{
    __shared__ __align__(16) unsigned char smem[64 * 68 * 4];   // 17408 B
    unsigned short* sA = (unsigned short*)smem;                 // 8 KB
    unsigned short* sB = (unsigned short*)(smem + 64 * 64 * 2); // 8 KB
    float* sC = (float*)smem;                                   // 17.4 KB (union)

    const int m0 = blockIdx.y * 64, n0 = blockIdx.x * 64;
    f32x4 acc[2][4] = {};
    gemm_core64<24, 2, 64>(x_ext, w_ext, m0, n0, sA, sB, acc);

    const int tid = threadIdx.x, w = tid >> 6, lane = tid & 63;
    const int quad = lane >> 4, r = lane & 15;
    const int wm = w >> 1, wn = w & 1;
    #pragma unroll
    for (int t = 0; t < 2; t++)
        #pragma unroll
        for (int u = 0; u < 2; u++)
            #pragma unroll
            for (int g = 0; g < 4; g++)
                sC[(wm * 32 + t * 16 + quad * 4 + g) * 68 + wn * 32 + u * 16 + r] = acc[t][u][g];
    __syncthreads();

    const int which = n0 >> 9;       // 0:q 1:k 2:v
    const int n0l = n0 & 511;        // = h0*64
    const int h0 = n0l >> 6;
    const int b = m0 >> 9, s0 = m0 & 511;

    if (which < 2) {
        const float scl = (which == 0) ? 0.125f : 1.0f;
        const float* bias = (which == 0) ? bq : bk;
        unsigned* dst = (unsigned*)((which == 0) ? q_ext : k_ext);
        #pragma unroll
        for (int seg = 0; seg < 3; seg++) {
            // q_ext row = [hi | lo | hi]; k_ext row = [hi | hi | lo]
            const bool lo = (which == 0) ? (seg == 1) : (seg == 2);
            #pragma unroll
            for (int it = 0; it < 8; it++) {
                const int idx = it * 256 + tid;        // 0..2047
                const int sl = idx >> 5;               // s-row 0..63
                const int jc = idx & 31;               // d pair
                const int nc = jc * 2;
                float v0 = (sC[sl * 68 + nc]     + bias[n0l + nc])     * scl;
                float v1 = (sC[sl * 68 + nc + 1] + bias[n0l + nc + 1]) * scl;
                unsigned short a0 = f2bf(v0), a1 = f2bf(v1);
                if (lo) { a0 = f2bf(v0 - bf2f(a0)); a1 = f2bf(v1 - bf2f(a1)); }
                const long orow = (long)(b * NH + h0) * SEQ + s0 + sl;
                dst[orow * 96 + seg * 32 + jc] = (unsigned)a0 | ((unsigned)a1 << 16);
            }
        }
    } else {
        unsigned* dst = (unsigned*)vT;
        #pragma unroll
        for (int it = 0; it < 8; it++) {
            const int idx = it * 256 + tid;
            const int d = idx >> 5;                    // 0..63
            const int jc = idx & 31;                   // s pair
            const int sl = jc * 2;
            const float bvv = bv[n0l + d];
            const float v0 = sC[sl * 68 + d] + bvv;
            const float v1 = sC[(sl + 1) * 68 + d] + bvv;
            const long orow = (long)(b * NH + h0) * DHD + d;
            dst[orow * 256 + (s0 >> 1) + jc] = (unsigned)f2bf(v0) | ((unsigned)f2bf(v1) << 16);
        }
    }
}

// ---------------- scores = q_ext @ k_ext^T per (b,h), K=192 -> fp16 ------
__global__ __launch_bounds__(256) void gemm_scores(
    const unsigned short* __restrict__ q_ext, const unsigned short* __restrict__ k_ext,
    unsigned short* __restrict__ scoresH)
{
    __shared__ __align__(16) unsigned short sA[64 * 64];
    __shared__ __align__(16) unsigned short sB[128 * 64];
    const int z = blockIdx.z;
    const int m0 = blockIdx.y * 64, n0 = blockIdx.x * 128;
    f32x4 acc[2][4] = {};
    gemm_core64<3, 4, 64>(q_ext + (long)z * SEQ * 192, k_ext + (long)z * SEQ * 192,
                          m0, n0, sA, sB, acc);

    const int tid = threadIdx.x, w = tid >> 6, lane = tid & 63;
    const int quad = lane >> 4, r = lane & 15;
    const int wm = w >> 1, wn = w & 1;
    // pack fp16 tile into LDS (reuse sB: 64x128 halves = 16 KB), then 16B stores
    unsigned short* hC = sB;
    #pragma unroll
    for (int t = 0; t < 2; t++)
        #pragma unroll
        for (int u = 0; u < 4; u++)
            #pragma unroll
            for (int g = 0; g < 4; g++) {
                const int ml = wm * 32 + t * 16 + quad * 4 + g;
                const int nl = wn * 64 + u * 16 + r;
                hC[ml * 128 + nl] = ftof16(fminf(fmaxf(acc[t][u][g], -15.f), 15.f));
            }
    __syncthreads();
    #pragma unroll
    for (int it = 0; it < 4; it++) {
        const int id = it * 256 + tid;       // 0..1023
        const int ml = id >> 4, ch = id & 15;
        *(uint4*)(scoresH + ((long)z * SEQ + m0 + ml) * SEQ + n0 + ch * 8) =
            *(const uint4*)(hC + ml * 128 + ch * 8);
    }
}

// ---------------- out = out_tmp @ wo^T + bo (32x64 tiles) ----------------
__global__ __launch_bounds__(256) void gemm_proj(
    const unsigned short* __restrict__ otmp, const unsigned short* __restrict__ woh,
    const float* __restrict__ bo, float* __restrict__ out)
{
    __shared__ __align__(16) unsigned short sA[32 * 64];
    __shared__ __align__(16) unsigned short sB[64 * 64];
    const int m0 = blockIdx.y * 32, n0 = blockIdx.x * 64;
    f32x4 acc[2][4] = {};
    gemm_core64<8, 2, 32>(otmp, woh, m0, n0, sA, sB, acc);
    const int tid = threadIdx.x, w = tid >> 6, lane = tid & 63;
    const int quad = lane >> 4, r = lane & 15;
    const int wm = w >> 1, wn = w & 1;
    #pragma unroll
    for (int u = 0; u < 2; u++)
        #pragma unroll
        for (int g = 0; g < 4; g++) {
            const int m = m0 + wm * 16 + quad * 4 + g;
            const int n = n0 + wn * 32 + u * 16 + r;
            out[(long)m * EMB + n] = acc[0][u][g] + bo[n];
        }
}

// ---------------- block reduction helpers (blockDim=256, 4 waves) --------
__device__ __forceinline__ float blockReduceSum(float v, float* sred) {
    #pragma unroll
    for (int o = 32; o > 0; o >>= 1) v += __shfl_down(v, o);
    __syncthreads();
    if ((threadIdx.x & 63) == 0) sred[threadIdx.x >> 6] = v;
    __syncthreads();
    return (sred[0] + sred[1]) + (sred[2] + sred[3]);
}
// packed 4-component sum reduce: one barrier pair instead of four
__device__ __forceinline__ float4 blockReduceSum4(float4 v, float4* s4) {
    #pragma unroll
    for (int o = 32; o > 0; o >>= 1) {
        v.x += __shfl_down(v.x, o); v.y += __shfl_down(v.y, o);
        v.z += __shfl_down(v.z, o); v.w += __shfl_down(v.w, o);
    }
    __syncthreads();
    if ((threadIdx.x & 63) == 0) s4[threadIdx.x >> 6] = v;
    __syncthreads();
    float4 r;
    r.x = (s4[0].x + s4[1].x) + (s4[2].x + s4[3].x);
    r.y = (s4[0].y + s4[1].y) + (s4[2].y + s4[3].y);
    r.z = (s4[0].z + s4[1].z) + (s4[2].z + s4[3].z);
    r.w = (s4[0].w + s4[1].w) + (s4[2].w + s4[3].w);
    return r;
}

// ---------------- fused prep: LUT + ext-K split builds (float4) ----------
__global__ __launch_bounds__(256) void prep_kernel(
    const float* __restrict__ x,
    const float* __restrict__ wq, const float* __restrict__ wk,
    const float* __restrict__ wv, const float* __restrict__ wo,
    const float* __restrict__ w1, const float* __restrict__ b1,
    const float* __restrict__ w2, const float* __restrict__ b2,
    unsigned short* __restrict__ x_ext, unsigned short* __restrict__ w_ext,
    unsigned short* __restrict__ woh, float* __restrict__ lut)
{
    const int blk = blockIdx.x;
    if (blk < 9) {
        const int i = blk * 256 + threadIdx.x;
        if (i > LUTN) return;
        const float xv = XMIN + i * XSTEP;
        float a = 0.f;
        for (int h = 0; h < HIDN; h++) {
            float hv = xv * w1[h] + b1[h];
            hv = fminf(fmaxf(hv, -5.f), 5.f);
            hv = fmaxf(hv, 0.f);
            a += hv * w2[h];
        }
        a += b2[0];
        a = fminf(fmaxf(a, -5.f), 5.f);
        const float taylor = fminf(fmaxf(1.f + 2.5f * a, 0.5f), 1.5f);
        lut[i] = 1.f / (1.f + expf(-taylor));
        return;
    }
    const int i = (blk - 9) * 256 + threadIdx.x;   // quad index, 0..524287
    if (i < 262144) {
        // x path: row m (512 floats = 128 quads) -> x_ext row [xh|xl|xh]
        const int m = i >> 7, kq = i & 127;
        const float4 v = ((const float4*)x)[i];
        const unsigned short h0 = f2bf(v.x), h1 = f2bf(v.y), h2 = f2bf(v.z), h3 = f2bf(v.w);
        const unsigned hi01 = (unsigned)h0 | ((unsigned)h1 << 16);
        const unsigned hi23 = (unsigned)h2 | ((unsigned)h3 << 16);
        const unsigned lo01 = (unsigned)f2bf(v.x - bf2f(h0)) | ((unsigned)f2bf(v.y - bf2f(h1)) << 16);
        const unsigned lo23 = (unsigned)f2bf(v.z - bf2f(h2)) | ((unsigned)f2bf(v.w - bf2f(h3)) << 16);
        unsigned* dst = (unsigned*)x_ext;
        const long base = (long)m * 768 + kq * 2;
        dst[base] = hi01;       dst[base + 1] = hi23;       // xh
        dst[base + 256] = lo01; dst[base + 257] = lo23;     // xl
        dst[base + 512] = hi01; dst[base + 513] = hi23;     // xh
    } else if (i < 458752) {
        // w path: row n of stacked [wq;wk;wv] -> w_ext row [wh|wh|wl]
        const int j = i - 262144;                   // 0..196607
        const int n = j >> 7, kq = j & 127;
        const float4 v = (j < 65536) ? ((const float4*)wq)[j]
                       : (j < 131072 ? ((const float4*)wk)[j - 65536]
                                     : ((const float4*)wv)[j - 131072]);
        const unsigned short h0 = f2bf(v.x), h1 = f2bf(v.y), h2 = f2bf(v.z), h3 = f2bf(v.w);
        const unsigned hi01 = (unsigned)h0 | ((unsigned)h1 << 16);
        const unsigned hi23 = (unsigned)h2 | ((unsigned)h3 << 16);
        const unsigned lo01 = (unsigned)f2bf(v.x - bf2f(h0)) | ((unsigned)f2bf(v.y - bf2f(h1)) << 16);
        const unsigned lo23 = (unsigned)f2bf(v.z - bf2f(h2)) | ((unsigned)f2bf(v.w - bf2f(h3)) << 16);
        unsigned* dst = (unsigned*)w_ext;
        const long base = (long)n * 768 + kq * 2;
        dst[base] = hi01;       dst[base + 1] = hi23;       // wh
        dst[base + 256] = hi01; dst[base + 257] = hi23;     // wh
        dst[base + 512] = lo01; dst[base + 513] = lo23;     // wl
    } else {
        const int j = i - 458752;                   // 0..65535
        const float4 v = ((const float4*)wo)[j];
        unsigned* dst = (unsigned*)woh;
        dst[j * 2]     = (unsigned)f2bf(v.x) | ((unsigned)f2bf(v.y) << 16);
        dst[j * 2 + 1] = (unsigned)f2bf(v.z) | ((unsigned)f2bf(v.w) << 16);
    }
}

// ---------------- transform kernel: one block per (b,i) row --------------
// Max-subtractions removed: mean-attn clamped to [-10,10] and entropy term
// in [0,1.1], so unshifted expf is fp32-safe -> 2 fewer reduce rounds.
__global__ __launch_bounds__(256) void transform_kernel(
    const unsigned short* __restrict__ scoresH, // [B,H,S,S] fp16 (clamped)
    const float* __restrict__ lut,              // [LUTN+1]
    unsigned short* __restrict__ t0H,           // [B,S,S] fp16
    float4* __restrict__ partials)              // [B*S] float4 slots
{
    const int rr = blockIdx.x;
    const int b = rr >> 9, i = rr & 511;
    const int tid = threadIdx.x;

    __shared__ float slut[LUTN + 1];
    __shared__ float sred[4];
    __shared__ float4 sred4[4];

    for (int u = tid; u <= LUTN; u += 256) slut[u] = lut[u];

    // mean over heads: packed fp16 pair loads (j = 2*tid, 2*tid+1)
    const unsigned* baseU =
        (const unsigned*)(scoresH + (((long)(b * NH)) * SEQ + i) * SEQ) + tid;
    float s0 = 0.f, s1 = 0.f;
    #pragma unroll
    for (int h = 0; h < NH; h++) {
        const unsigned pv = baseU[h * (SEQ * SEQ / 2)];
        s0 += f16tof((unsigned short)pv);
        s1 += f16tof((unsigned short)(pv >> 16));
    }
    float mv[2] = { s0 * 0.125f, s1 * 0.125f };
    __syncthreads();

    float sigv[2], ex[2];
    float lsum = 0.f;
    #pragma unroll
    for (int u = 0; u < 2; u++) {
        const float m = mv[u];
        const float x = fminf(fmaxf(m, -8.f), 8.f) * EPSS;
        float t = (x - XMIN) * (1.0f / XSTEP);
        int idx = (int)t;
        idx = idx < 0 ? 0 : (idx > LUTN - 1 ? LUTN - 1 : idx);
        const float frac = t - (float)idx;
        const float l0 = slut[idx], l1 = slut[idx + 1];
        sigv[u] = l0 + frac * (l1 - l0);
        ex[u] = expf(fminf(fmaxf(m, -10.f), 10.f));   // |arg|<=10: safe unshifted
        lsum += ex[u];
    }
    const float rsum = blockReduceSum(lsum, sred);
    const float inv = 1.f / rsum;

    float ex2[2], lsum2 = 0.f;
    #pragma unroll
    for (int u = 0; u < 2; u++) {
        const float p = ex[u] * inv;
        const float he = -p * logf(p + 1e-6f);
        ex2[u] = expf(3.f * he);                      // arg in [0,1.1]: safe
        lsum2 += ex2[u];
    }
    const float rsum2 = blockReduceSum(lsum2, sred);
    const float inv2 = 1.f / rsum2;

    float tv[2];
    #pragma unroll
    for (int u = 0; u < 2; u++) tv[u] = sigv[u] * (ex2[u] * inv2);
    ((unsigned*)t0H)[((long)b * SEQ + i) * (SEQ / 2) + tid] =
        (unsigned)ftof16(tv[0]) | ((unsigned)ftof16(tv[1]) << 16);

    float4 pv;
    pv.x = mv[0] + mv[1];
    pv.y = mv[0] * mv[0] + mv[1] * mv[1];
    pv.z = tv[0] + tv[1];
    pv.w = tv[0] * tv[0] + tv[1] * tv[1];
    const float4 rs = blockReduceSum4(pv, sred4);
    if (tid == 0) partials[rr] = rs;
}

// ---------------- fused coef + softmax + attn@v --------------------------
// Grid (16 m-tiles of 32 rows, 32 z=(b,h)). LDS packed to exactly 40 KB
// (attnS unpadded+XOR-swizzled, sC/sred4 unioned) -> 4 blocks/CU.
__global__ __launch_bounds__(256) void softmax_attnv(
    const unsigned short* __restrict__ scoresH, // [B,H,S,S] fp16
    const unsigned short* __restrict__ t0H,     // [B,S,S] fp16
    const float4* __restrict__ partials,        // [B*S]
    const unsigned short* __restrict__ vT,      // [B,H,DH,S] bf16
    unsigned short* __restrict__ otmp)          // [B*S, E] bf16
{
    __shared__ __align__(16) unsigned char smem[40960];
    unsigned short* attnS = (unsigned short*)smem;            // [32][512] bf16, XOR-swz
    unsigned short* sB    = (unsigned short*)(smem + 32768);  // [64][64] V tile
    float*  sC    = (float*)smem;                             // [32][66] epilogue (union)
    float4* sred4 = (float4*)smem;                            // phase A scratch (union)

    const int m0 = blockIdx.x * 32;
    const int z  = blockIdx.y;
    const int b  = z >> 3, h = z & 7;
    const int tid = threadIdx.x, wv = tid >> 6, lane = tid & 63;

    // --- phase A: coef (redundant per block) ---
    const float4 p0 = partials[b * SEQ + tid];
    const float4 p1 = partials[b * SEQ + tid + 256];
    float4 pv4 = make_float4(p0.x + p1.x, p0.y + p1.y, p0.z + p1.z, p0.w + p1.w);
    const float4 rs4 = blockReduceSum4(pv4, sred4);
    const float sm = rs4.x, sm2 = rs4.y, st = rs4.z, st2 = rs4.w;
    const float n = (float)SEQ * (float)SEQ;
    const float gamma = fminf(fmaxf((sqrtf(sm2) + 1e-4f) / (sqrtf(st2) + 1e-4f), 0.8f), 1.2f);
    const float o_mean = sm / n, t0m = st / n;
    const float o_std = sqrtf(fmaxf(fmaxf(sm2 / n - o_mean * o_mean, 0.f), 0.01f));
    const float t_std = sqrtf(fmaxf(gamma * gamma * fmaxf(st2 / n - t0m * t0m, 0.f), 0.01f));
    const float gdyn = fminf(fmaxf(o_std / t_std, 0.8f), 1.2f);
    const float c1 = gdyn * gamma;
    const float c0 = o_mean - c1 * t0m;
    __syncthreads();   // sred4 reads done before attnS (same bytes) is written

    // V staging: issue step-0 NOW; latency hides under phase B's loads+expf
    const int lrow = lane >> 3, lc = lane & 7;
    const int scw = lc ^ lrow;
    const unsigned short* bg0 = vT + (long)z * DHD * SEQ + (long)(wv * 16 + lrow) * SEQ + scw * 8;
    const unsigned short* bg1 = bg0 + 8 * SEQ;
    unsigned short* dB0 = sB + (wv * 16) * 64;
    unsigned short* dB1 = sB + (wv * 16 + 8) * 64;
    async_lds16(bg0, dB0);
    async_lds16(bg1, dB1);

    // --- phase B: softmax 32 rows -> LDS bf16 tile (unshifted exp: s<=15) ---
    const int j0 = lane * 8;
    for (int it = 0; it < 8; it++) {
        const int rowl = it * 4 + wv;
        const bf16x8 sr = *(const bf16x8*)(scoresH + ((long)z * SEQ + m0 + rowl) * SEQ + j0);
        const bf16x8 tr = *(const bf16x8*)(t0H + ((long)b * SEQ + m0 + rowl) * SEQ + j0);
        float sv[8];
        float lsum = 0.f;
        #pragma unroll
        for (int u = 0; u < 8; u++) {
            float s = f16tof((unsigned short)sr[u])
                    + ALPHA * (c0 + c1 * f16tof((unsigned short)tr[u]));
            s = fminf(fmaxf(s, -15.f), 15.f);
            sv[u] = expf(s);                      // exp(15)=3.3e6: fp32-safe
            lsum += sv[u];
        }
        #pragma unroll
        for (int o = 32; o > 0; o >>= 1) lsum += __shfl_down(lsum, o);
        lsum = __shfl(lsum, 0);
        const float inv = 1.f / lsum;
        bf16x8 pk;
        #pragma unroll
        for (int u = 0; u < 8; u++) pk[u] = (short)f2bf(sv[u] * inv);
        *(bf16x8*)(attnS + rowl * 512 + (j0 ^ ((rowl & 7) << 3))) = pk;
    }

    // --- phase C: attn(LDS) @ vT (single buffer; stage(s+1) post-barrier) ---
    const int quad = lane >> 4, r = lane & 15;
    const int wm = wv >> 1, wn = wv & 1;
    const int arow = wm * 16 + r;
    const int aswz = (arow & 7) << 3;
    f32x4 acc[2] = {};
    for (int s = 0; s < 8; s++) {
        __syncthreads();       // stage(s) drained; s==0 also makes attnS visible
        const int k0 = s * 64;
        #pragma unroll
        for (int kc = 0; kc < 2; kc++) {
            const bf16x8 a = *(const bf16x8*)(attnS + arow * 512 + ((k0 + kc * 32 + quad * 8) ^ aswz));
            #pragma unroll
            for (int u = 0; u < 2; u++) {
                const int row = wn * 32 + u * 16 + r;
                const bf16x8 bb = *(const bf16x8*)(sB + row * 64 + ((kc * 4 + quad) ^ (row & 7)) * 8);
                acc[u] = MFMA(a, bb, acc[u]);
            }
        }
        __syncthreads();       // all waves done reading sB for step s
        if (s < 7) { async_lds16(bg0 + (s + 1) * 64, dB0); async_lds16(bg1 + (s + 1) * 64, dB1); }
    }

    // --- phase D: epilogue (sC overlays attnS; all reads done at last barrier) ---
    #pragma unroll
    for (int u = 0; u < 2; u++)
        #pragma unroll
        for (int g = 0; g < 4; g++)
            sC[(wm * 16 + quad * 4 + g) * 66 + wn * 32 + u * 16 + r] = acc[u][g];
    __syncthreads();
    unsigned* dst = (unsigned*)otmp;
    #pragma unroll
    for (int it = 0; it < 4; it++) {
        const int idx = it * 256 + tid;
        const int sr2 = idx >> 5, jc = idx & 31;
        const float v0 = sC[sr2 * 66 + jc * 2], v1 = sC[sr2 * 66 + jc * 2 + 1];
        dst[((long)(b * SEQ + m0 + sr2)) * 256 + h * 32 + jc] =
            (unsigned)f2bf(v0) | ((unsigned)f2bf(v1) << 16);
    }
}

// -------------------------------------------------------------------------
extern "C" void kernel_launch(void* const* d_in, const int* in_sizes, int n_in,
                              void* d_out, int out_size, void* d_ws, size_t ws_size,
                              hipStream_t stream) {
    const float* x  = (const float*)d_in[0];
    const float* wq = (const float*)d_in[1];
    const float* bq = (const float*)d_in[2];
    const float* wk = (const float*)d_in[3];
    const float* bk = (const float*)d_in[4];
    const float* wv = (const float*)d_in[5];
    const float* bv = (const float*)d_in[6];
    const float* wo = (const float*)d_in[7];
    const float* bo = (const float*)d_in[8];
    const float* w1 = (const float*)d_in[9];
    const float* b1 = (const float*)d_in[10];
    const float* w2 = (const float*)d_in[11];
    const float* b2 = (const float*)d_in[12];
    float* out = (float*)d_out;

    // ---- workspace layout (~48 MB) ----
    char* wsb = (char*)d_ws;
    unsigned short* scoresH = (unsigned short*)wsb;        // 16 MB [B,H,S,S] fp16
    unsigned short* t0H     = scoresH + 8388608;           // 2 MB  [B,S,S] fp16
    float4* partials = (float4*)(t0H + 1048576);           // 32 KB
    float*  lutbuf   = (float*)(partials + 2048);
    unsigned short* u16 = (unsigned short*)(wsb + (20u << 20));
    unsigned short* x_ext = u16;                           // 6 MB   [2048,1536]
    unsigned short* w_ext = x_ext + 3145728;               // 4.5 MB [1536,1536]
    unsigned short* q_ext = w_ext + 2359296;               // 6 MB   [B*H*S,192]
    unsigned short* k_ext = q_ext + 3145728;               // 6 MB
    unsigned short* vT    = k_ext + 3145728;               // 2 MB   [B,H,DH,S]
    unsigned short* otmp  = vT + 1048576;                  // 2 MB   [B*S, E]
    unsigned short* woh   = otmp + 1048576;                // 0.5 MB [E,E]

    // 1) prep: LUT + ext-K split builds (float4-vectorized)
    prep_kernel<<<dim3(9 + 2048), dim3(256), 0, stream>>>(
        x, wq, wk, wv, wo, w1, b1, w2, b2, x_ext, w_ext, woh, lutbuf);

    // 2) fused QKV projection (compensated bf16, K=1536, BK=64)
    gemm_qkv<<<dim3(24, 32), dim3(256), 0, stream>>>(
        x_ext, w_ext, bq, bk, bv, q_ext, k_ext, vT);

    // 3) scores = q @ k^T per (b,h) (compensated, K=192) -> fp16, clamp
    gemm_scores<<<dim3(4, 8, 32), dim3(256), 0, stream>>>(q_ext, k_ext, scoresH);

    // 4) autopoietic transform (LUT-based, atomic-free, fp16 I/O)
    transform_kernel<<<dim3(BATCH * SEQ), dim3(256), 0, stream>>>(
        scoresH, lutbuf, t0H, partials);

    // 5) fused coef + residual/softmax + attn@v (fp16 in, BK=64, 40KB LDS)
    softmax_attnv<<<dim3(16, 32), dim3(256), 0, stream>>>(
        scoresH, t0H, partials, vT, otmp);

    // 6) out = out_tmp @ wo^T + bo (32x64 tiles, 512 blocks)
    gemm_proj<<<dim3(8, 64), dim3(256), 0, stream>>>(otmp, woh, bo, out);
}